// Round 1
// baseline (2052.749 us; speedup 1.0000x reference)
//
#include <hip/hip_runtime.h>

#define NN 100000
#define NE 1600000

static inline int cdiv(long long a, int b) { return (int)((a + b - 1) / b); }

// ---- degree / dinv -------------------------------------------------------
__global__ void deg_count_kernel(const int* __restrict__ col, float* __restrict__ deg, int E) {
    int e = blockIdx.x * blockDim.x + threadIdx.x;
    if (e < E) atomicAdd(&deg[col[e]], 1.0f);
}

__global__ void dinv_kernel(float* __restrict__ deg, int N) {
    int i = blockIdx.x * blockDim.x + threadIdx.x;
    if (i < N) deg[i] = rsqrtf(deg[i] + 1.0f);
}

// ---- dense h = x @ W (W cached in LDS) -----------------------------------
template <int FIN, int FOUT>
__global__ void gemm_kernel(const float* __restrict__ x, const float* __restrict__ W,
                            float* __restrict__ h, int N) {
    __shared__ float Ws[FIN * FOUT];
    for (int i = threadIdx.x; i < FIN * FOUT; i += blockDim.x) Ws[i] = W[i];
    __syncthreads();
    int idx = blockIdx.x * blockDim.x + threadIdx.x;
    int node = idx / FOUT;
    int j = idx % FOUT;
    if (node >= N) return;
    const float* xr = x + (size_t)node * FIN;
    float s = 0.f;
#pragma unroll
    for (int k = 0; k < FIN; k++) s += xr[k] * Ws[k * FOUT + j];
    h[(size_t)node * FOUT + j] = s;
}

// ---- agg = dinv^2 * h (self-loop term) -----------------------------------
template <int F>
__global__ void self_init_kernel(const float* __restrict__ h, const float* __restrict__ dinv,
                                 float* __restrict__ agg, int N) {
    int idx = blockIdx.x * blockDim.x + threadIdx.x;
    if (idx >= N * F) return;
    int node = idx / F;
    float d = dinv[node];
    agg[idx] = d * d * h[idx];
}

// ---- edge scatter: agg[col] += dinv[row]*dinv[col]*h[row] ----------------
template <int F>
__global__ void scatter_kernel(const int* __restrict__ row, const int* __restrict__ col,
                               const float* __restrict__ h, const float* __restrict__ dinv,
                               float* __restrict__ agg, int E) {
    int idx = blockIdx.x * blockDim.x + threadIdx.x;
    if (idx >= E * F) return;       // E*F <= 204.8M < 2^31
    int e = idx / F;                // F is constexpr -> magic-mul division
    int f = idx - e * F;
    int r = row[e];
    int c = col[e];
    float nrm = dinv[r] * dinv[c];
    atomicAdd(&agg[c * F + f], nrm * h[r * F + f]);
}

// ---- out = [relu](agg + b) ----------------------------------------------
template <int F, bool RELU>
__global__ void bias_kernel(const float* __restrict__ agg, const float* __restrict__ b,
                            float* __restrict__ out, int N) {
    int idx = blockIdx.x * blockDim.x + threadIdx.x;
    if (idx >= N * F) return;
    int f = idx % F;
    float v = agg[idx] + b[f];
    out[idx] = RELU ? fmaxf(v, 0.f) : v;
}

extern "C" void kernel_launch(void* const* d_in, const int* in_sizes, int n_in,
                              void* d_out, int out_size, void* d_ws, size_t ws_size,
                              hipStream_t stream) {
    const float* x  = (const float*)d_in[0];
    const int*   ei = (const int*)d_in[1];
    const float* W1 = (const float*)d_in[2]; const float* b1 = (const float*)d_in[3];
    const float* W2 = (const float*)d_in[4]; const float* b2 = (const float*)d_in[5];
    const float* W3 = (const float*)d_in[6]; const float* b3 = (const float*)d_in[7];
    const float* W4 = (const float*)d_in[8]; const float* b4 = (const float*)d_in[9];
    const int* row = ei;
    const int* col = ei + NE;

    float* A    = (float*)d_ws;                 // N x 128
    float* B    = A + (size_t)NN * 128;         // N x 128
    float* dinv = B + (size_t)NN * 128;         // N   (deg, then rsqrt in place)
    float* out  = (float*)d_out;

    const int BS = 256;

    hipMemsetAsync(dinv, 0, NN * sizeof(float), stream);
    deg_count_kernel<<<cdiv(NE, BS), BS, 0, stream>>>(col, dinv, NE);
    dinv_kernel<<<cdiv(NN, BS), BS, 0, stream>>>(dinv, NN);

    // Layer 1: x(d_in,21) -> h=A(32) -> agg=B -> relu(B)
    gemm_kernel<21, 32><<<cdiv((long long)NN * 32, BS), BS, 0, stream>>>(x, W1, A, NN);
    self_init_kernel<32><<<cdiv((long long)NN * 32, BS), BS, 0, stream>>>(A, dinv, B, NN);
    scatter_kernel<32><<<cdiv((long long)NE * 32, BS), BS, 0, stream>>>(row, col, A, dinv, B, NE);
    bias_kernel<32, true><<<cdiv((long long)NN * 32, BS), BS, 0, stream>>>(B, b1, B, NN);

    // Layer 2: x=B(32) -> h=A(64) -> agg=B -> relu(B)
    gemm_kernel<32, 64><<<cdiv((long long)NN * 64, BS), BS, 0, stream>>>(B, W2, A, NN);
    self_init_kernel<64><<<cdiv((long long)NN * 64, BS), BS, 0, stream>>>(A, dinv, B, NN);
    scatter_kernel<64><<<cdiv((long long)NE * 64, BS), BS, 0, stream>>>(row, col, A, dinv, B, NE);
    bias_kernel<64, true><<<cdiv((long long)NN * 64, BS), BS, 0, stream>>>(B, b2, B, NN);

    // Layer 3: x=B(64) -> h=A(128) -> agg=B -> relu(B)
    gemm_kernel<64, 128><<<cdiv((long long)NN * 128, BS), BS, 0, stream>>>(B, W3, A, NN);
    self_init_kernel<128><<<cdiv((long long)NN * 128, BS), BS, 0, stream>>>(A, dinv, B, NN);
    scatter_kernel<128><<<cdiv((long long)NE * 128, BS), BS, 0, stream>>>(row, col, A, dinv, B, NE);
    bias_kernel<128, true><<<cdiv((long long)NN * 128, BS), BS, 0, stream>>>(B, b3, B, NN);

    // Layer 4: x=B(128) -> h=A(21) -> agg=d_out -> +b4 (no relu)
    gemm_kernel<128, 21><<<cdiv((long long)NN * 21, BS), BS, 0, stream>>>(B, W4, A, NN);
    self_init_kernel<21><<<cdiv((long long)NN * 21, BS), BS, 0, stream>>>(A, dinv, out, NN);
    scatter_kernel<21><<<cdiv((long long)NE * 21, BS), BS, 0, stream>>>(row, col, A, dinv, out, NE);
    bias_kernel<21, false><<<cdiv((long long)NN * 21, BS), BS, 0, stream>>>(out, b4, out, NN);
}

// Round 2
// 1281.466 us; speedup vs baseline: 1.6019x; 1.6019x over previous
//
#include <hip/hip_runtime.h>

#define NN 100000
#define NE 1600000

static inline int cdiv(long long a, int b) { return (int)((a + b - 1) / b); }

// ---- histogram of destination counts (also the degree) -------------------
__global__ void hist_kernel(const int* __restrict__ col, int* __restrict__ cnt, int E) {
    int e = blockIdx.x * blockDim.x + threadIdx.x;
    if (e < E) atomicAdd(&cnt[col[e]], 1);
}

__global__ void dinv_kernel(const int* __restrict__ cnt, float* __restrict__ dinv, int N) {
    int i = blockIdx.x * blockDim.x + threadIdx.x;
    if (i < N) dinv[i] = rsqrtf((float)cnt[i] + 1.0f);
}

// ---- single-block exclusive scan (100k elems, ~10us) ---------------------
__global__ void scan_kernel(const int* __restrict__ cnt, int* __restrict__ rowptr,
                            int* __restrict__ cursor, int N) {
    __shared__ int tmp[1024];
    __shared__ int running;
    if (threadIdx.x == 0) running = 0;
    __syncthreads();
    for (int base = 0; base < N; base += 1024) {
        int i = base + threadIdx.x;
        int v = (i < N) ? cnt[i] : 0;
        tmp[threadIdx.x] = v;
        __syncthreads();
        for (int off = 1; off < 1024; off <<= 1) {
            int t = (threadIdx.x >= off) ? tmp[threadIdx.x - off] : 0;
            __syncthreads();
            tmp[threadIdx.x] += t;
            __syncthreads();
        }
        int excl = tmp[threadIdx.x] - v;
        if (i < N) {
            int val = running + excl;
            rowptr[i] = val;
            cursor[i] = val;
        }
        __syncthreads();
        if (threadIdx.x == 1023) running += tmp[1023];
        __syncthreads();
    }
    if (threadIdx.x == 0) rowptr[N] = running;
}

// ---- fill CSR (sorted by col) with per-edge weight -----------------------
__global__ void fill_csr_kernel(const int* __restrict__ row, const int* __restrict__ col,
                                const float* __restrict__ dinv, int* __restrict__ cursor,
                                int* __restrict__ csr_row, float* __restrict__ csr_w, int E) {
    int e = blockIdx.x * blockDim.x + threadIdx.x;
    if (e >= E) return;
    int c = col[e];
    int r = row[e];
    int pos = atomicAdd(&cursor[c], 1);
    csr_row[pos] = r;
    csr_w[pos] = dinv[r] * dinv[c];
}

// ---- pull gather: out[c] = sum_e w_e * h[row_e] + dinv[c]^2 * h[c] (+b) --
template <int F, bool BIAS>
__global__ void gather_kernel(const float* __restrict__ h, const int* __restrict__ rowptr,
                              const int* __restrict__ csr_row, const float* __restrict__ csr_w,
                              const float* __restrict__ dinv, const float* __restrict__ bias,
                              float* __restrict__ out, int N) {
    int node = blockIdx.x * blockDim.y + threadIdx.y;
    if (node >= N) return;
    int f = threadIdx.x;  // blockDim.x >= F
    int s = rowptr[node];
    int e = rowptr[node + 1];
    float acc = 0.f;
    for (int i = s; i < e; i++) {
        int r = csr_row[i];        // same addr across lanes -> broadcast
        float w = csr_w[i];
        if (f < F) acc += w * h[(size_t)r * F + f];
    }
    if (f < F) {
        float d = dinv[node];
        float v = acc + d * d * h[(size_t)node * F + f];
        if (BIAS) v += bias[f];
        out[(size_t)node * F + f] = v;
    }
}

// ---- dense h = x @ W (+b, relu), W cached in LDS -------------------------
template <int FIN, int FOUT, bool BIAS, bool RELU>
__global__ void gemm_kernel(const float* __restrict__ x, const float* __restrict__ W,
                            const float* __restrict__ b, float* __restrict__ h, int N) {
    __shared__ float Ws[FIN * FOUT];
    __shared__ float bs[FOUT];
    for (int i = threadIdx.x; i < FIN * FOUT; i += blockDim.x) Ws[i] = W[i];
    if (BIAS) for (int i = threadIdx.x; i < FOUT; i += blockDim.x) bs[i] = b[i];
    __syncthreads();
    int idx = blockIdx.x * blockDim.x + threadIdx.x;
    int node = idx / FOUT;
    int j = idx - node * FOUT;
    if (node >= N) return;
    const float* xr = x + (size_t)node * FIN;
    float s = 0.f;
#pragma unroll
    for (int k = 0; k < FIN; k++) s += xr[k] * Ws[k * FOUT + j];
    if (BIAS) s += bs[j];
    if (RELU) s = fmaxf(s, 0.f);
    h[(size_t)node * FOUT + j] = s;
}

extern "C" void kernel_launch(void* const* d_in, const int* in_sizes, int n_in,
                              void* d_out, int out_size, void* d_ws, size_t ws_size,
                              hipStream_t stream) {
    const float* x  = (const float*)d_in[0];
    const int*   ei = (const int*)d_in[1];
    const float* W1 = (const float*)d_in[2]; const float* b1 = (const float*)d_in[3];
    const float* W2 = (const float*)d_in[4]; const float* b2 = (const float*)d_in[5];
    const float* W3 = (const float*)d_in[6]; const float* b3 = (const float*)d_in[7];
    const float* W4 = (const float*)d_in[8]; const float* b4 = (const float*)d_in[9];
    const int* row = ei;
    const int* col = ei + NE;
    float* out = (float*)d_out;

    // workspace layout
    float* A      = (float*)d_ws;                  // N x 128
    float* B      = A + (size_t)NN * 128;          // N x 128
    float* dinv   = B + (size_t)NN * 128;          // N
    float* csr_w  = dinv + NN;                     // E
    int*   cnt    = (int*)(csr_w + NE);            // N
    int*   rowptr = cnt + NN;                      // N+1
    int*   cursor = rowptr + NN + 1;               // N
    int*   csr_row= cursor + NN;                   // E

    const int BS = 256;

    // ---- CSR + dinv setup ----
    hipMemsetAsync(cnt, 0, NN * sizeof(int), stream);
    hist_kernel<<<cdiv(NE, BS), BS, 0, stream>>>(col, cnt, NE);
    dinv_kernel<<<cdiv(NN, BS), BS, 0, stream>>>(cnt, dinv, NN);
    scan_kernel<<<1, 1024, 0, stream>>>(cnt, rowptr, cursor, NN);
    fill_csr_kernel<<<cdiv(NE, BS), BS, 0, stream>>>(row, col, dinv, cursor, csr_row, csr_w, NE);

    // ---- Layer 1: agg(x)[21] -> gemm 21->32 +b1 relu ----
    {
        dim3 blk(32, 8);
        gather_kernel<21, false><<<cdiv(NN, 8), blk, 0, stream>>>(x, rowptr, csr_row, csr_w, dinv, nullptr, B, NN);
        gemm_kernel<21, 32, true, true><<<cdiv((long long)NN * 32, BS), BS, 0, stream>>>(B, W1, b1, A, NN);
    }
    // ---- Layer 2: agg(h1)[32] -> gemm 32->64 +b2 relu ----
    {
        dim3 blk(32, 8);
        gather_kernel<32, false><<<cdiv(NN, 8), blk, 0, stream>>>(A, rowptr, csr_row, csr_w, dinv, nullptr, B, NN);
        gemm_kernel<32, 64, true, true><<<cdiv((long long)NN * 64, BS), BS, 0, stream>>>(B, W2, b2, A, NN);
    }
    // ---- Layer 3: agg(h2)[64] -> gemm 64->128 +b3 relu ----
    {
        dim3 blk(64, 4);
        gather_kernel<64, false><<<cdiv(NN, 4), blk, 0, stream>>>(A, rowptr, csr_row, csr_w, dinv, nullptr, B, NN);
        gemm_kernel<64, 128, true, true><<<cdiv((long long)NN * 128, BS), BS, 0, stream>>>(B, W3, b3, A, NN);
    }
    // ---- Layer 4: gemm 128->21 (no bias) -> agg[21] + b4 ----
    {
        gemm_kernel<128, 21, false, false><<<cdiv((long long)NN * 21, BS), BS, 0, stream>>>(A, W4, nullptr, B, NN);
        dim3 blk(32, 8);
        gather_kernel<21, true><<<cdiv(NN, 8), blk, 0, stream>>>(B, rowptr, csr_row, csr_w, dinv, b4, out, NN);
    }
}

// Round 3
// 553.263 us; speedup vs baseline: 3.7103x; 2.3162x over previous
//
#include <hip/hip_runtime.h>

#define NN 100000
#define NE 1600000

static inline int cdiv(long long a, int b) { return (int)((a + b - 1) / b); }

// ======================= CSR build =======================================
__global__ void hist_kernel(const int* __restrict__ col, int* __restrict__ cnt, int E) {
    int e = blockIdx.x * blockDim.x + threadIdx.x;
    if (e < E) atomicAdd(&cnt[col[e]], 1);
}

__global__ void dinv_kernel(const int* __restrict__ cnt, float* __restrict__ dinv, int N) {
    int i = blockIdx.x * blockDim.x + threadIdx.x;
    if (i < N) dinv[i] = rsqrtf((float)cnt[i] + 1.0f);
}

// phase A: 256 thr/block, 512 elems/block; exclusive scan within block -> rowptr,
// block total -> bsum[b]
__global__ void scan_blocks(const int* __restrict__ cnt, int* __restrict__ rowptr,
                            int* __restrict__ bsum, int N) {
    int t = threadIdx.x;
    int base = blockIdx.x * 512;
    int i0 = base + 2 * t, i1 = i0 + 1;
    int v0 = (i0 < N) ? cnt[i0] : 0;
    int v1 = (i1 < N) ? cnt[i1] : 0;
    int s = v0 + v1;
    int lane = t & 63, wv = t >> 6;
    int incl = s;
#pragma unroll
    for (int off = 1; off < 64; off <<= 1) {
        int u = __shfl_up(incl, off, 64);
        if (lane >= off) incl += u;
    }
    __shared__ int wtot[4];
    if (lane == 63) wtot[wv] = incl;
    __syncthreads();
    int woff = 0;
    for (int w = 0; w < wv; w++) woff += wtot[w];
    int excl = woff + incl - s;
    if (i0 < N) rowptr[i0] = excl;
    if (i1 < N) rowptr[i1] = excl + v0;
    if (t == 255) bsum[blockIdx.x] = woff + incl;
}

// phase B: exclusive scan of block sums (G <= 256), single block
__global__ void scan_bsums(int* __restrict__ bsum, int G) {
    int t = threadIdx.x;
    int v = (t < G) ? bsum[t] : 0;
    int lane = t & 63, wv = t >> 6;
    int incl = v;
#pragma unroll
    for (int off = 1; off < 64; off <<= 1) {
        int u = __shfl_up(incl, off, 64);
        if (lane >= off) incl += u;
    }
    __shared__ int wtot[4];
    if (lane == 63) wtot[wv] = incl;
    __syncthreads();
    int woff = 0;
    for (int w = 0; w < wv; w++) woff += wtot[w];
    if (t < G) bsum[t] = woff + incl - v;
}

// phase C: add block offsets, copy to cursor, set rowptr[N]
__global__ void scan_finish(int* __restrict__ rowptr, const int* __restrict__ bsum,
                            int* __restrict__ cursor, int N) {
    int i = blockIdx.x * blockDim.x + threadIdx.x;
    if (i < N) {
        int v = rowptr[i] + bsum[i >> 9];
        rowptr[i] = v;
        cursor[i] = v;
    }
    if (i == 0) rowptr[N] = NE;
}

__global__ void fill_csr_kernel(const int* __restrict__ row, const int* __restrict__ col,
                                const float* __restrict__ dinv, int* __restrict__ cursor,
                                int* __restrict__ csr_row, float* __restrict__ csr_w, int E) {
    int e = blockIdx.x * blockDim.x + threadIdx.x;
    if (e >= E) return;
    int c = col[e];
    int r = row[e];
    int pos = atomicAdd(&cursor[c], 1);
    csr_row[pos] = r;
    csr_w[pos] = dinv[r] * dinv[c];
}

// ======================= x pad copy (21 -> stride 32) ====================
__global__ void padx_kernel(const float* __restrict__ x, float* __restrict__ x32, int N) {
    int idx = blockIdx.x * blockDim.x + threadIdx.x;
    if (idx >= N * 21) return;
    int n = idx / 21;
    int k = idx - n * 21;
    x32[n * 32 + k] = x[idx];
}

// ======================= pull gather (float4 rows) =======================
// row stride in floats = 4*LPN. blockDim = (LPN, 256/LPN).
template <int LPN, bool BIAS, bool STORE21>
__global__ void gather4_kernel(const float4* __restrict__ h, const int* __restrict__ rowptr,
                               const int* __restrict__ csr_row, const float* __restrict__ csr_w,
                               const float* __restrict__ dinv, const float* __restrict__ bias,
                               float* __restrict__ outp, int N) {
    int node = blockIdx.x * blockDim.y + threadIdx.y;
    if (node >= N) return;
    int l = threadIdx.x;
    int s = rowptr[node], e = rowptr[node + 1];
    float4 acc = make_float4(0.f, 0.f, 0.f, 0.f);
    int i = s;
    for (; i + 1 < e; i += 2) {
        int r0 = csr_row[i];
        int r1 = csr_row[i + 1];
        float w0 = csr_w[i];
        float w1 = csr_w[i + 1];
        float4 a = h[(size_t)r0 * LPN + l];
        float4 c = h[(size_t)r1 * LPN + l];
        acc.x = fmaf(w0, a.x, acc.x); acc.y = fmaf(w0, a.y, acc.y);
        acc.z = fmaf(w0, a.z, acc.z); acc.w = fmaf(w0, a.w, acc.w);
        acc.x = fmaf(w1, c.x, acc.x); acc.y = fmaf(w1, c.y, acc.y);
        acc.z = fmaf(w1, c.z, acc.z); acc.w = fmaf(w1, c.w, acc.w);
    }
    if (i < e) {
        int r0 = csr_row[i];
        float w0 = csr_w[i];
        float4 a = h[(size_t)r0 * LPN + l];
        acc.x = fmaf(w0, a.x, acc.x); acc.y = fmaf(w0, a.y, acc.y);
        acc.z = fmaf(w0, a.z, acc.z); acc.w = fmaf(w0, a.w, acc.w);
    }
    float d = dinv[node];
    float dd = d * d;
    float4 hs = h[(size_t)node * LPN + l];
    acc.x = fmaf(dd, hs.x, acc.x); acc.y = fmaf(dd, hs.y, acc.y);
    acc.z = fmaf(dd, hs.z, acc.z); acc.w = fmaf(dd, hs.w, acc.w);
    if (STORE21) {
        int j = 4 * l;
        float v[4] = {acc.x, acc.y, acc.z, acc.w};
#pragma unroll
        for (int c = 0; c < 4; c++) {
            int jj = j + c;
            if (jj < 21) outp[(size_t)node * 21 + jj] = v[c] + (BIAS ? bias[jj] : 0.f);
        }
    } else {
        ((float4*)outp)[(size_t)node * LPN + l] = acc;
    }
}

// ======================= register-tiled GEMM =============================
// out[n][j] = relu(sum_k x[n][k] * W[k][j] + b[j]); x stride XSTRIDE, out stride OSTRIDE.
template <int FIN, int FOUT, int FOUTP, int NT, int RJ, bool BIAS, bool RELU,
          int XSTRIDE, int OSTRIDE>
__global__ void gemm_tiled(const float* __restrict__ x, const float* __restrict__ W,
                           const float* __restrict__ b, float* __restrict__ out, int N) {
    constexpr int JG = FOUTP / RJ;       // j-groups
    constexpr int NG = 256 / JG;         // node-groups
    constexpr int RN = NT / NG;          // nodes per thread
    constexpr int XLD = FIN + 1;         // padded LDS stride for x
    __shared__ float xs[NT * XLD];
    __shared__ float Ws[FIN * FOUTP];
    __shared__ float bs[FOUTP];
    const int t = threadIdx.x;
    const int node0 = blockIdx.x * NT;

    // stage W (pad columns to FOUTP with zeros)
    for (int i = t; i < FIN * FOUT; i += 256) {
        int k = i / FOUT;
        int j = i - k * FOUT;
        Ws[k * FOUTP + j] = W[i];
    }
    if (FOUTP > FOUT) {
        for (int i = t; i < FIN * (FOUTP - FOUT); i += 256) {
            int k = i / (FOUTP - FOUT);
            int j = i - k * (FOUTP - FOUT);
            Ws[k * FOUTP + FOUT + j] = 0.f;
        }
    }
    if (t < FOUTP) bs[t] = (BIAS && t < FOUT) ? b[t] : 0.f;

    // stage x tile
    if (FIN % 4 == 0) {
        constexpr int F4 = FIN / 4;
        for (int i = t; i < NT * F4; i += 256) {
            int n = i / F4;
            int kk = i - n * F4;
            int node = node0 + n;
            float4 v = (node < N) ? ((const float4*)x)[(size_t)node * (XSTRIDE / 4) + kk]
                                  : make_float4(0.f, 0.f, 0.f, 0.f);
            xs[n * XLD + 4 * kk + 0] = v.x;
            xs[n * XLD + 4 * kk + 1] = v.y;
            xs[n * XLD + 4 * kk + 2] = v.z;
            xs[n * XLD + 4 * kk + 3] = v.w;
        }
    } else {
        for (int i = t; i < NT * FIN; i += 256) {
            int n = i / FIN;
            int k = i - n * FIN;
            int node = node0 + n;
            xs[n * XLD + k] = (node < N) ? x[(size_t)node * XSTRIDE + k] : 0.f;
        }
    }
    __syncthreads();

    const int jg = t % JG;
    const int ng = t / JG;
    float acc[RN][RJ];
#pragma unroll
    for (int r = 0; r < RN; r++)
#pragma unroll
        for (int jj = 0; jj < RJ; jj++) acc[r][jj] = 0.f;

#pragma unroll 2
    for (int k = 0; k < FIN; k++) {
        float wv[RJ];
        if (RJ % 4 == 0) {
#pragma unroll
            for (int c = 0; c < RJ / 4; c++) {
                float4 w = *(const float4*)&Ws[k * FOUTP + jg * RJ + 4 * c];
                wv[4 * c + 0] = w.x; wv[4 * c + 1] = w.y;
                wv[4 * c + 2] = w.z; wv[4 * c + 3] = w.w;
            }
        } else {
#pragma unroll
            for (int c = 0; c < RJ / 2; c++) {
                float2 w = *(const float2*)&Ws[k * FOUTP + jg * RJ + 2 * c];
                wv[2 * c + 0] = w.x; wv[2 * c + 1] = w.y;
            }
        }
        float xv[RN];
#pragma unroll
        for (int r = 0; r < RN; r++) xv[r] = xs[(ng * RN + r) * XLD + k];
#pragma unroll
        for (int r = 0; r < RN; r++)
#pragma unroll
            for (int jj = 0; jj < RJ; jj++) acc[r][jj] = fmaf(xv[r], wv[jj], acc[r][jj]);
    }

    // epilogue
#pragma unroll
    for (int r = 0; r < RN; r++) {
        int node = node0 + ng * RN + r;
        if (node >= N) continue;
        float* orow = out + (size_t)node * OSTRIDE + jg * RJ;
#pragma unroll
        for (int jj = 0; jj < RJ; jj++) {
            float v = acc[r][jj] + bs[jg * RJ + jj];
            if (RELU) v = fmaxf(v, 0.f);
            acc[r][jj] = v;
        }
        if (RJ % 4 == 0 && OSTRIDE % 4 == 0) {
#pragma unroll
            for (int c = 0; c < RJ / 4; c++) {
                *(float4*)&orow[4 * c] =
                    make_float4(acc[r][4 * c], acc[r][4 * c + 1], acc[r][4 * c + 2], acc[r][4 * c + 3]);
            }
        } else {
#pragma unroll
            for (int jj = 0; jj < RJ; jj++) orow[jj] = acc[r][jj];
        }
    }
}

// ======================= launch ==========================================
extern "C" void kernel_launch(void* const* d_in, const int* in_sizes, int n_in,
                              void* d_out, int out_size, void* d_ws, size_t ws_size,
                              hipStream_t stream) {
    const float* x  = (const float*)d_in[0];
    const int*   ei = (const int*)d_in[1];
    const float* W1 = (const float*)d_in[2]; const float* b1 = (const float*)d_in[3];
    const float* W2 = (const float*)d_in[4]; const float* b2 = (const float*)d_in[5];
    const float* W3 = (const float*)d_in[6]; const float* b3 = (const float*)d_in[7];
    const float* W4 = (const float*)d_in[8]; const float* b4 = (const float*)d_in[9];
    const int* row = ei;
    const int* col = ei + NE;
    float* out = (float*)d_out;

    // workspace layout (floats)
    float* A      = (float*)d_ws;                  // N x 128
    float* B      = A + (size_t)NN * 128;          // N x 128 (also x32 staging)
    float* dinv   = B + (size_t)NN * 128;          // N
    float* csr_w  = dinv + NN;                     // E
    int*   cnt    = (int*)(csr_w + NE);            // N
    int*   rowptr = cnt + NN;                      // N+1
    int*   cursor = rowptr + NN + 1;               // N
    int*   csr_row= cursor + NN;                   // E
    int*   bsum   = csr_row + NE;                  // 256

    const int BS = 256;
    const int SCAN_G = cdiv(NN, 512);  // 196

    // ---- CSR + dinv ----
    hipMemsetAsync(cnt, 0, NN * sizeof(int), stream);
    hist_kernel<<<cdiv(NE, BS), BS, 0, stream>>>(col, cnt, NE);
    dinv_kernel<<<cdiv(NN, BS), BS, 0, stream>>>(cnt, dinv, NN);
    scan_blocks<<<SCAN_G, 256, 0, stream>>>(cnt, rowptr, bsum, NN);
    scan_bsums<<<1, 256, 0, stream>>>(bsum, SCAN_G);
    scan_finish<<<cdiv(NN, BS), BS, 0, stream>>>(rowptr, bsum, cursor, NN);
    fill_csr_kernel<<<cdiv(NE, BS), BS, 0, stream>>>(row, col, dinv, cursor, csr_row, csr_w, NE);

    // ---- pad x into B (stride 32) ----
    padx_kernel<<<cdiv((long long)NN * 21, BS), BS, 0, stream>>>(x, B, NN);

    // ---- Layer 1: gather(x32) [B->A], gemm 21->32 +b relu [A->B, stride 32] ----
    {
        dim3 blk(8, 32);
        gather4_kernel<8, false, false><<<cdiv(NN, 32), blk, 0, stream>>>(
            (const float4*)B, rowptr, csr_row, csr_w, dinv, nullptr, A, NN);
        gemm_tiled<21, 32, 32, 64, 8, true, true, 32, 32><<<cdiv(NN, 64), 256, 0, stream>>>(
            A, W1, b1, B, NN);
    }
    // ---- Layer 2: gather(h1) [B->A], gemm 32->64 +b relu [A->B, stride 64] ----
    {
        dim3 blk(8, 32);
        gather4_kernel<8, false, false><<<cdiv(NN, 32), blk, 0, stream>>>(
            (const float4*)B, rowptr, csr_row, csr_w, dinv, nullptr, A, NN);
        gemm_tiled<32, 64, 64, 64, 8, true, true, 32, 64><<<cdiv(NN, 64), 256, 0, stream>>>(
            A, W2, b2, B, NN);
    }
    // ---- Layer 3: gather(h2) [B->A], gemm 64->128 +b relu [A->B, stride 128] ----
    {
        dim3 blk(16, 16);
        gather4_kernel<16, false, false><<<cdiv(NN, 16), blk, 0, stream>>>(
            (const float4*)B, rowptr, csr_row, csr_w, dinv, nullptr, A, NN);
        gemm_tiled<64, 128, 128, 64, 8, true, true, 64, 128><<<cdiv(NN, 64), 256, 0, stream>>>(
            A, W3, b3, B, NN);
    }
    // ---- Layer 4: gemm 128->21 [B->A, stride 32], gather+b4 [A->out, stride 21] ----
    {
        gemm_tiled<128, 21, 24, 64, 6, false, false, 128, 32><<<cdiv(NN, 64), 256, 0, stream>>>(
            B, W4, nullptr, A, NN);
        dim3 blk(8, 32);
        gather4_kernel<8, true, true><<<cdiv(NN, 32), blk, 0, stream>>>(
            (const float4*)A, rowptr, csr_row, csr_w, dinv, b4, out, NN);
    }
}